// Round 3
// baseline (355.939 us; speedup 1.0000x reference)
//
#include <hip/hip_runtime.h>
#include <hip/hip_bf16.h>
#include <stdint.h>

#define BATCH 2048
#define FDIM 512
#define CDIM 64

typedef unsigned short ushort_t;
typedef __attribute__((ext_vector_type(8))) short short8;
typedef __attribute__((ext_vector_type(4))) float f32x4;

__device__ __forceinline__ ushort_t f2bf(float x) {
    union { float f; uint32_t u; } v; v.f = x;
    uint32_t u = v.u;
    uint32_t r = u + 0x7FFFu + ((u >> 16) & 1u);  // round-to-nearest-even
    return (ushort_t)(r >> 16);
}
__device__ __forceinline__ float bf2f(ushort_t u) {
    union { float f; uint32_t v; } x; x.v = ((uint32_t)u) << 16; return x.f;
}

// ---- fused fp32->bf16 convert: W_proj (8192 blocks), f_feat (512), t_feat (512) ----
__global__ void convert_all_kernel(const float* __restrict__ W, ushort_t* __restrict__ Wb,
                                   const float* __restrict__ f, ushort_t* __restrict__ f16,
                                   const float* __restrict__ t, ushort_t* __restrict__ t16) {
    int blk = blockIdx.x;
    const float* src; ushort_t* dst; int idx;
    if (blk < 8192)      { src = W; dst = Wb;  idx = blk * 256 + threadIdx.x; }
    else if (blk < 8704) { src = f; dst = f16; idx = (blk - 8192) * 256 + threadIdx.x; }
    else                 { src = t; dst = t16; idx = (blk - 8704) * 256 + threadIdx.x; }
    float4 v0 = ((const float4*)src)[idx * 2];
    float4 v1 = ((const float4*)src)[idx * 2 + 1];
    ushort_t p[8] = { f2bf(v0.x), f2bf(v0.y), f2bf(v0.z), f2bf(v0.w),
                      f2bf(v1.x), f2bf(v1.y), f2bf(v1.z), f2bf(v1.w) };
    *(uint4*)&dst[idx * 8] = *(uint4*)p;
}

// ---- no-LDS direct-fragment GEMM ----
// u[b,n] = sum_j f16[b,j] * Wb[n,j];  n = c*512 + i
// MFMA 16x16x32 A-frag: lane holds row=l15,       k=lg*8..+8  -> contiguous 16B of f16 row
//               B-frag: lane holds row=l15*4+ni,  k=lg*8..+8  -> contiguous 16B of Wb row
// (B rows fed permuted so D frag ni, col l15 -> n_local = l15*4+ni: epilogue = one ushort4 of t16)
// No __shared__ tiles, no barriers in the K-loop: latency hidden by 3 blocks/CU free-running.

#define LOADK(Ad, Bd, koff)                                                         \
    { _Pragma("unroll")                                                             \
      for (int mi = 0; mi < 4; mi++) Ad[mi] = *(const short8*)(pA[mi] + (koff));    \
      _Pragma("unroll")                                                             \
      for (int ni = 0; ni < 4; ni++) Bd[ni] = *(const short8*)(pB[ni] + (koff)); }

#define MFMAK(Av, Bv)                                                               \
    { _Pragma("unroll")                                                             \
      for (int mi = 0; mi < 4; mi++) {                                              \
        _Pragma("unroll")                                                           \
        for (int ni = 0; ni < 4; ni++)                                              \
          acc[mi][ni] = __builtin_amdgcn_mfma_f32_16x16x32_bf16(                    \
              Av[mi], Bv[ni], acc[mi][ni], 0, 0, 0);                                \
      } }

__launch_bounds__(256, 3)
__global__ void gemm_fused_kernel(const ushort_t* __restrict__ f16,
                                  const ushort_t* __restrict__ Wb,
                                  const ushort_t* __restrict__ t16,
                                  float* __restrict__ part) {
    __shared__ float scratch[128 * 2];

    const int tid  = threadIdx.x;
    const int wave = tid >> 6;
    const int lane = tid & 63;
    const int l15  = lane & 15;
    const int lg   = lane >> 4;
    const int wm   = wave >> 1;   // 0..1 (M half, 64 rows)
    const int wn   = wave & 1;    // 0..1 (N half, 64 cols)

    // XCD-chunked bijective swizzle, m fastest within each XCD:
    // grid 4096 = 16 m-chunks x 256 n-panels; each XCD owns 32 consecutive n-panels
    // (B slice 4 MiB -> its private L2) and sweeps all m sharing the 2 MiB A panel.
    const int xcd = blockIdx.x & 7;
    const int idx = blockIdx.x >> 3;          // 0..511
    const int bx  = idx & 15;                 // m chunk (fastest)
    const int by  = xcd * 32 + (idx >> 4);    // n panel
    const int b0  = bx * 128;
    const int n0  = by * 128;

    // per-lane fragment base pointers (k offset applied as +koff elements)
    const ushort_t* pA[4];
    const ushort_t* pB[4];
    #pragma unroll
    for (int mi = 0; mi < 4; mi++)
        pA[mi] = f16 + (size_t)(b0 + wm * 64 + mi * 16 + l15) * FDIM + lg * 8;
    #pragma unroll
    for (int ni = 0; ni < 4; ni++)
        pB[ni] = Wb + (size_t)(n0 + wn * 64 + l15 * 4 + ni) * FDIM + lg * 8;

    f32x4 acc[4][4];
    #pragma unroll
    for (int mi = 0; mi < 4; mi++)
        #pragma unroll
        for (int ni = 0; ni < 4; ni++)
            acc[mi][ni] = (f32x4){0.f, 0.f, 0.f, 0.f};

    short8 A0[4], B0[4], A1[4], B1[4];

    LOADK(A0, B0, 0)
    #pragma unroll 1
    for (int k = 0; k < FDIM; k += 64) {
        LOADK(A1, B1, k + 32)              // prefetch next ksub
        MFMAK(A0, B0)
        LOADK(A0, B0, (k + 64) & 511)      // prefetch ksub after (wraps harmlessly on last)
        MFMAK(A1, B1)
    }

    // epilogue: contract with t16; frag ni, col l15 -> i = (n0&511) + wn*64 + l15*4 + ni
    const int c      = n0 >> 9;
    const int iq     = (n0 >> 7) & 3;
    const int i_base = (n0 & 511) + wn * 64 + l15 * 4;
    #pragma unroll
    for (int mi = 0; mi < 4; mi++) {
        const int row_blk = wm * 64 + mi * 16 + lg * 4;
        #pragma unroll
        for (int r = 0; r < 4; r++) {
            ushort4 tv = *(const ushort4*)&t16[(size_t)(b0 + row_blk + r) * FDIM + i_base];
            float sv = acc[mi][0][r] * bf2f(tv.x) + acc[mi][1][r] * bf2f(tv.y)
                     + acc[mi][2][r] * bf2f(tv.z) + acc[mi][3][r] * bf2f(tv.w);
            sv += __shfl_xor(sv, 1, 64);
            sv += __shfl_xor(sv, 2, 64);
            sv += __shfl_xor(sv, 4, 64);
            sv += __shfl_xor(sv, 8, 64);
            if (l15 == 0) scratch[(row_blk + r) * 2 + wn] = sv;
        }
    }
    __syncthreads();
    if (tid < 128) {
        float2 s2 = *(const float2*)&scratch[tid * 2];
        part[(((size_t)(b0 + tid)) * CDIM + c) * 4 + iq] = s2.x + s2.y;
    }
}

// ---- MLP head: part[b][c][4] quarters -> relu(proj) -> relu(W1) -> W2 ----
__global__ void mlp_kernel(const float* __restrict__ part,
                           const float* __restrict__ b_proj,
                           const float* __restrict__ W1, const float* __restrict__ b1,
                           const float* __restrict__ W2, const float* __restrict__ b2,
                           float* __restrict__ out) {
    __shared__ float h[8][64];
    const int tid = threadIdx.x;
    const int bl  = tid >> 5;        // 0..7
    const int o   = tid & 31;
    const int b   = blockIdx.x * 8 + bl;

    #pragma unroll
    for (int c = o; c < 64; c += 32) {
        float4 v = *(const float4*)&part[(((size_t)b * 64 + c)) * 4];
        float sv = v.x + v.y + v.z + v.w + b_proj[c];
        h[bl][c] = sv > 0.f ? sv : 0.f;
    }
    __syncthreads();

    float sv = b1[o];
    #pragma unroll
    for (int c = 0; c < 64; c++) sv += h[bl][c] * W1[o * 64 + c];
    float v = (sv > 0.f ? sv : 0.f) * W2[o];
    v += __shfl_xor(v, 1, 32);
    v += __shfl_xor(v, 2, 32);
    v += __shfl_xor(v, 4, 32);
    v += __shfl_xor(v, 8, 32);
    v += __shfl_xor(v, 16, 32);
    if (o == 0) out[b] = v + b2[0];
}

extern "C" void kernel_launch(void* const* d_in, const int* in_sizes, int n_in,
                              void* d_out, int out_size, void* d_ws, size_t ws_size,
                              hipStream_t stream) {
    const float* t_feat = (const float*)d_in[0];
    const float* f_feat = (const float*)d_in[1];
    const float* W_proj = (const float*)d_in[2];
    const float* b_proj = (const float*)d_in[3];
    const float* W1     = (const float*)d_in[4];
    const float* b1     = (const float*)d_in[5];
    const float* W2     = (const float*)d_in[6];
    const float* b2     = (const float*)d_in[7];
    float* out = (float*)d_out;

    uint8_t* ws = (uint8_t*)d_ws;
    ushort_t* Wb   = (ushort_t*)(ws);                          // 32 MiB
    ushort_t* f16  = (ushort_t*)(ws + 33554432);               // 2 MiB
    ushort_t* t16  = (ushort_t*)(ws + 33554432 + 2097152);     // 2 MiB
    float*    part = (float*)(ws + 33554432 + 2 * 2097152);    // 2 MiB

    convert_all_kernel<<<dim3(9216), dim3(256), 0, stream>>>(W_proj, Wb, f_feat, f16, t_feat, t16);

    gemm_fused_kernel<<<dim3((BATCH / 128) * ((CDIM * FDIM) / 128)), dim3(256), 0, stream>>>(
        f16, Wb, t16, part);

    mlp_kernel<<<dim3(BATCH / 8), dim3(256), 0, stream>>>(part, b_proj, W1, b1, W2, b2, out);
}

// Round 4
// 239.667 us; speedup vs baseline: 1.4851x; 1.4851x over previous
//
#include <hip/hip_runtime.h>
#include <hip/hip_bf16.h>
#include <stdint.h>

#define BATCH 2048
#define FDIM 512
#define CDIM 64

typedef unsigned short ushort_t;
typedef __attribute__((ext_vector_type(8))) short short8;
typedef __attribute__((ext_vector_type(4))) float f32x4;

__device__ __forceinline__ ushort_t f2bf(float x) {
    union { float f; uint32_t u; } v; v.f = x;
    uint32_t u = v.u;
    uint32_t r = u + 0x7FFFu + ((u >> 16) & 1u);  // round-to-nearest-even
    return (ushort_t)(r >> 16);
}
__device__ __forceinline__ float bf2f(ushort_t u) {
    union { float f; uint32_t v; } x; x.v = ((uint32_t)u) << 16; return x.f;
}

// ---- fused fp32->bf16 convert: W_proj (8192 blocks), f_feat (512), t_feat (512) ----
__global__ void convert_all_kernel(const float* __restrict__ W, ushort_t* __restrict__ Wb,
                                   const float* __restrict__ f, ushort_t* __restrict__ f16,
                                   const float* __restrict__ t, ushort_t* __restrict__ t16) {
    int blk = blockIdx.x;
    const float* src; ushort_t* dst; int idx;
    if (blk < 8192)      { src = W; dst = Wb;  idx = blk * 256 + threadIdx.x; }
    else if (blk < 8704) { src = f; dst = f16; idx = (blk - 8192) * 256 + threadIdx.x; }
    else                 { src = t; dst = t16; idx = (blk - 8704) * 256 + threadIdx.x; }
    float4 v0 = ((const float4*)src)[idx * 2];
    float4 v1 = ((const float4*)src)[idx * 2 + 1];
    ushort_t p[8] = { f2bf(v0.x), f2bf(v0.y), f2bf(v0.z), f2bf(v0.w),
                      f2bf(v1.x), f2bf(v1.y), f2bf(v1.z), f2bf(v1.w) };
    *(uint4*)&dst[idx * 8] = *(uint4*)p;
}

#define AS3(p) ((__attribute__((address_space(3))) void*)(p))
#define AS1(p) ((const __attribute__((address_space(1))) void*)(p))

// ---- 128x128 tile, BK=64, LDS double-buffer, depth-1 counted vmcnt(8), raw barriers.
// u[b,n] = sum_j f16[b,j]*Wb[n,j]; n = c*512+i; epilogue contracts with t16[b,i].
// LDS rows 128B (64 bf16) = 8 chunks of 16B; phys chunk = global chunk ^ (row&7):
// 8-lane ds_read phases hit 8 distinct 16B slots = all 32 banks (conflict-free);
// staging keeps LINEAR dest + inverse-swizzled per-lane SOURCE (same involution).

#define STAGE(buf, kt)                                                              \
    { _Pragma("unroll")                                                             \
      for (int l = 0; l < 4; l++)                                                   \
        __builtin_amdgcn_global_load_lds(AS1(gA[l] + (kt) * 64),                    \
            AS3(&As[buf][l * 2048 + wave * 512]), 16, 0, 0);                        \
      _Pragma("unroll")                                                             \
      for (int l = 0; l < 4; l++)                                                   \
        __builtin_amdgcn_global_load_lds(AS1(gB[l] + (kt) * 64),                    \
            AS3(&Bs[buf][l * 2048 + wave * 512]), 16, 0, 0); }

#define COMPUTE(buf)                                                                \
    { short8 a[4][2], b[4][2];                                                      \
      _Pragma("unroll")                                                             \
      for (int mi = 0; mi < 4; mi++) {                                              \
        a[mi][0] = *(const short8*)&As[buf][a_off[mi][0]];                          \
        a[mi][1] = *(const short8*)&As[buf][a_off[mi][1]];                          \
      }                                                                             \
      _Pragma("unroll")                                                             \
      for (int ni = 0; ni < 4; ni++) {                                              \
        b[ni][0] = *(const short8*)&Bs[buf][b_off[ni][0]];                          \
        b[ni][1] = *(const short8*)&Bs[buf][b_off[ni][1]];                          \
      }                                                                             \
      _Pragma("unroll")                                                             \
      for (int ks = 0; ks < 2; ks++) {                                              \
        _Pragma("unroll")                                                           \
        for (int mi = 0; mi < 4; mi++) {                                            \
          _Pragma("unroll")                                                         \
          for (int ni = 0; ni < 4; ni++)                                            \
            acc[mi][ni] = __builtin_amdgcn_mfma_f32_16x16x32_bf16(                  \
                a[mi][ks], b[ni][ks], acc[mi][ni], 0, 0, 0);                        \
        }                                                                           \
      } }

// wait for everything EXCEPT the 8 just-issued prefetch loads, then barrier.
#define BAR_WAIT8                                                                   \
    asm volatile("s_waitcnt vmcnt(8)" ::: "memory");                                \
    __builtin_amdgcn_s_barrier();                                                   \
    __builtin_amdgcn_sched_barrier(0);

#define BAR_POST                                                                    \
    __builtin_amdgcn_s_barrier();                                                   \
    __builtin_amdgcn_sched_barrier(0);

__launch_bounds__(256, 2)
__global__ void gemm_fused_kernel(const ushort_t* __restrict__ f16,
                                  const ushort_t* __restrict__ Wb,
                                  const ushort_t* __restrict__ t16,
                                  float* __restrict__ part) {
    __shared__ ushort_t As[2][128 * 64];   // 2 x 16 KiB
    __shared__ ushort_t Bs[2][128 * 64];   // 2 x 16 KiB
    __shared__ float scratch[256];

    const int tid  = threadIdx.x;
    const int wave = tid >> 6;
    const int lane = tid & 63;
    const int l15  = lane & 15;
    const int lg   = lane >> 4;
    const int wm   = wave >> 1;   // 0..1 (M half, 64 rows)
    const int wn   = wave & 1;    // 0..1 (N half, 64 cols)

    // XCD-chunked bijective swizzle, m fastest within each XCD (B slice 4 MiB/XCD-L2).
    const int xcd = blockIdx.x & 7;
    const int idx = blockIdx.x >> 3;          // 0..511
    const int bx  = idx & 15;                 // m chunk (fastest)
    const int by  = xcd * 32 + (idx >> 4);    // n panel
    const int b0  = bx * 128;
    const int n0  = by * 128;

    // staging: slot s = l*256+tid -> LDS element s*8 (linear dest);
    // content: row = s>>3, global chunk gc = (s&7) ^ (row&7).
    const ushort_t* gA[4];
    const ushort_t* gB[4];
    #pragma unroll
    for (int l = 0; l < 4; l++) {
        int s   = l * 256 + tid;
        int row = s >> 3;
        int gc  = (s & 7) ^ (row & 7);
        gA[l] = f16 + (size_t)(b0 + row) * FDIM + gc * 8;
        // B row-permute: phys row q holds n_local = (q&64) | ((q&15)<<2) | ((q>>4)&3)
        int bq = (row & 64) | ((row & 15) << 2) | ((row >> 4) & 3);
        gB[l] = Wb + (size_t)(n0 + bq) * FDIM + gc * 8;
    }

    // fragment ds_read offsets (elements); all accesses statically unrolled
    int a_off[4][2], b_off[4][2];
    #pragma unroll
    for (int mi = 0; mi < 4; mi++) {
        int r = wm * 64 + mi * 16 + l15;
        #pragma unroll
        for (int ks = 0; ks < 2; ks++)
            a_off[mi][ks] = r * 64 + ((ks * 4 + lg) ^ (r & 7)) * 8;
    }
    #pragma unroll
    for (int ni = 0; ni < 4; ni++) {
        int q = wn * 64 + ni * 16 + l15;
        #pragma unroll
        for (int ks = 0; ks < 2; ks++)
            b_off[ni][ks] = q * 64 + ((ks * 4 + lg) ^ (q & 7)) * 8;
    }

    f32x4 acc[4][4];
    #pragma unroll
    for (int mi = 0; mi < 4; mi++)
        #pragma unroll
        for (int ni = 0; ni < 4; ni++)
            acc[mi][ni] = (f32x4){0.f, 0.f, 0.f, 0.f};

    // pipeline: tiles 0..7; stage t+1 while computing t; vmcnt(8) = prev tile's stage done
    STAGE(0, 0)
    #pragma unroll 1
    for (int t = 0; t < 3; t++) {
        const int kt = t * 2;
        STAGE(1, kt + 1) BAR_WAIT8 COMPUTE(0) BAR_POST
        STAGE(0, kt + 2) BAR_WAIT8 COMPUTE(1) BAR_POST
    }
    STAGE(1, 7) BAR_WAIT8 COMPUTE(0) BAR_POST
    asm volatile("s_waitcnt vmcnt(0)" ::: "memory");
    __builtin_amdgcn_s_barrier();
    __builtin_amdgcn_sched_barrier(0);
    COMPUTE(1)

    // epilogue: contract with t16; frag ni, col l15 -> i = (n0&511) + wn*64 + l15*4 + ni
    const int c      = n0 >> 9;
    const int iq     = (n0 >> 7) & 3;
    const int i_base = (n0 & 511) + wn * 64 + l15 * 4;
    #pragma unroll
    for (int mi = 0; mi < 4; mi++) {
        const int row_blk = wm * 64 + mi * 16 + lg * 4;
        #pragma unroll
        for (int r = 0; r < 4; r++) {
            ushort4 tv = *(const ushort4*)&t16[(size_t)(b0 + row_blk + r) * FDIM + i_base];
            float sv = acc[mi][0][r] * bf2f(tv.x) + acc[mi][1][r] * bf2f(tv.y)
                     + acc[mi][2][r] * bf2f(tv.z) + acc[mi][3][r] * bf2f(tv.w);
            sv += __shfl_xor(sv, 1, 64);
            sv += __shfl_xor(sv, 2, 64);
            sv += __shfl_xor(sv, 4, 64);
            sv += __shfl_xor(sv, 8, 64);
            if (l15 == 0) scratch[(row_blk + r) * 2 + wn] = sv;
        }
    }
    __syncthreads();
    if (tid < 128) {
        float2 s2 = *(const float2*)&scratch[tid * 2];
        part[(((size_t)(b0 + tid)) * CDIM + c) * 4 + iq] = s2.x + s2.y;
    }
}

// ---- MLP head: part[b][c][4] quarters -> relu(proj) -> relu(W1) -> W2 ----
__global__ void mlp_kernel(const float* __restrict__ part,
                           const float* __restrict__ b_proj,
                           const float* __restrict__ W1, const float* __restrict__ b1,
                           const float* __restrict__ W2, const float* __restrict__ b2,
                           float* __restrict__ out) {
    __shared__ float h[8][64];
    const int tid = threadIdx.x;
    const int bl  = tid >> 5;        // 0..7
    const int o   = tid & 31;
    const int b   = blockIdx.x * 8 + bl;

    #pragma unroll
    for (int c = o; c < 64; c += 32) {
        float4 v = *(const float4*)&part[(((size_t)b * 64 + c)) * 4];
        float sv = v.x + v.y + v.z + v.w + b_proj[c];
        h[bl][c] = sv > 0.f ? sv : 0.f;
    }
    __syncthreads();

    float sv = b1[o];
    #pragma unroll
    for (int c = 0; c < 64; c++) sv += h[bl][c] * W1[o * 64 + c];
    float v = (sv > 0.f ? sv : 0.f) * W2[o];
    v += __shfl_xor(v, 1, 32);
    v += __shfl_xor(v, 2, 32);
    v += __shfl_xor(v, 4, 32);
    v += __shfl_xor(v, 8, 32);
    v += __shfl_xor(v, 16, 32);
    if (o == 0) out[b] = v + b2[0];
}

extern "C" void kernel_launch(void* const* d_in, const int* in_sizes, int n_in,
                              void* d_out, int out_size, void* d_ws, size_t ws_size,
                              hipStream_t stream) {
    const float* t_feat = (const float*)d_in[0];
    const float* f_feat = (const float*)d_in[1];
    const float* W_proj = (const float*)d_in[2];
    const float* b_proj = (const float*)d_in[3];
    const float* W1     = (const float*)d_in[4];
    const float* b1     = (const float*)d_in[5];
    const float* W2     = (const float*)d_in[6];
    const float* b2     = (const float*)d_in[7];
    float* out = (float*)d_out;

    uint8_t* ws = (uint8_t*)d_ws;
    ushort_t* Wb   = (ushort_t*)(ws);                          // 32 MiB
    ushort_t* f16  = (ushort_t*)(ws + 33554432);               // 2 MiB
    ushort_t* t16  = (ushort_t*)(ws + 33554432 + 2097152);     // 2 MiB
    float*    part = (float*)(ws + 33554432 + 2 * 2097152);    // 2 MiB

    convert_all_kernel<<<dim3(9216), dim3(256), 0, stream>>>(W_proj, Wb, f_feat, f16, t_feat, t16);

    gemm_fused_kernel<<<dim3((BATCH / 128) * ((CDIM * FDIM) / 128)), dim3(256), 0, stream>>>(
        f16, Wb, t16, part);

    mlp_kernel<<<dim3(BATCH / 8), dim3(256), 0, stream>>>(part, b_proj, W1, b1, W2, b2, out);
}

// Round 7
// 209.612 us; speedup vs baseline: 1.6981x; 1.1434x over previous
//
#include <hip/hip_runtime.h>
#include <hip/hip_bf16.h>
#include <stdint.h>

#define BATCH 2048
#define FDIM 512
#define CDIM 64

typedef unsigned short ushort_t;
typedef __attribute__((ext_vector_type(8))) short short8;
typedef __attribute__((ext_vector_type(4))) float f32x4;

__device__ __forceinline__ ushort_t f2bf(float x) {
    union { float f; uint32_t u; } v; v.f = x;
    uint32_t u = v.u;
    uint32_t r = u + 0x7FFFu + ((u >> 16) & 1u);  // round-to-nearest-even
    return (ushort_t)(r >> 16);
}
__device__ __forceinline__ float bf2f(ushort_t u) {
    union { float f; uint32_t v; } x; x.v = ((uint32_t)u) << 16; return x.f;
}

// ---- fused fp32->bf16 convert: W_proj (8192 blocks), f_feat (512), t_feat (512) ----
__global__ void convert_all_kernel(const float* __restrict__ W, ushort_t* __restrict__ Wb,
                                   const float* __restrict__ f, ushort_t* __restrict__ f16,
                                   const float* __restrict__ t, ushort_t* __restrict__ t16) {
    int blk = blockIdx.x;
    const float* src; ushort_t* dst; int idx;
    if (blk < 8192)      { src = W; dst = Wb;  idx = blk * 256 + threadIdx.x; }
    else if (blk < 8704) { src = f; dst = f16; idx = (blk - 8192) * 256 + threadIdx.x; }
    else                 { src = t; dst = t16; idx = (blk - 8704) * 256 + threadIdx.x; }
    float4 v0 = ((const float4*)src)[idx * 2];
    float4 v1 = ((const float4*)src)[idx * 2 + 1];
    ushort_t p[8] = { f2bf(v0.x), f2bf(v0.y), f2bf(v0.z), f2bf(v0.w),
                      f2bf(v1.x), f2bf(v1.y), f2bf(v1.z), f2bf(v1.w) };
    *(uint4*)&dst[idx * 8] = *(uint4*)p;
}

#define AS3(p) ((__attribute__((address_space(3))) void*)(p))
#define AS1(p) ((const __attribute__((address_space(1))) void*)(p))

// ---- 128x128 tile, BK=32, double-buffered LDS, ONE __syncthreads per K-step.
//      Stage tile t+1 BEFORE computing tile t; the syncthreads drain (vmcnt 0 +
//      lgkmcnt 0 + barrier, full HIP semantics) lands AFTER the compute phase,
//      so staging latency is covered by compute. No raw barriers, no counted
//      vmcnt -> correctness decidable by inspection (R5/R6 races eliminated).
// u[b,n] = sum_j f16[b,j]*Wb[n,j]; n = c*512+i; epilogue contracts with t16[b,i].

#define STAGE(bi, kt)                                                               \
    __builtin_amdgcn_global_load_lds(AS1(gA0 + (kt) * 32), AS3(&As[bi][0 * 2048 + wave * 512]), 16, 0, 0); \
    __builtin_amdgcn_global_load_lds(AS1(gA1 + (kt) * 32), AS3(&As[bi][1 * 2048 + wave * 512]), 16, 0, 0); \
    __builtin_amdgcn_global_load_lds(AS1(gB0 + (kt) * 32), AS3(&Bs[bi][0 * 2048 + wave * 512]), 16, 0, 0); \
    __builtin_amdgcn_global_load_lds(AS1(gB1 + (kt) * 32), AS3(&Bs[bi][1 * 2048 + wave * 512]), 16, 0, 0);

#define COMPUTE(bi)                                                                 \
    { short8 a[4], b[4];                                                            \
      _Pragma("unroll")                                                             \
      for (int mi = 0; mi < 4; mi++) a[mi] = *(const short8*)&As[bi][a_off[mi]];    \
      _Pragma("unroll")                                                             \
      for (int ni = 0; ni < 4; ni++) b[ni] = *(const short8*)&Bs[bi][b_off[ni]];    \
      _Pragma("unroll")                                                             \
      for (int mi = 0; mi < 4; mi++) {                                              \
        _Pragma("unroll")                                                           \
        for (int ni = 0; ni < 4; ni++)                                              \
          acc[mi][ni] = __builtin_amdgcn_mfma_f32_16x16x32_bf16(                    \
              a[mi], b[ni], acc[mi][ni], 0, 0, 0);                                  \
      } }

__launch_bounds__(256, 4)
__global__ void gemm_fused_kernel(const ushort_t* __restrict__ f16,
                                  const ushort_t* __restrict__ Wb,
                                  const ushort_t* __restrict__ t16,
                                  float* __restrict__ part) {
    __shared__ ushort_t As[2][128 * 32];   // 2 x 8 KiB
    __shared__ ushort_t Bs[2][128 * 32];   // 2 x 8 KiB
    __shared__ float scratch[256];         // 33 KiB total -> 4 blocks/CU

    const int tid  = threadIdx.x;
    const int wave = tid >> 6;
    const int lane = tid & 63;
    const int l15  = lane & 15;
    const int lg   = lane >> 4;

    const int m_base = (wave >> 1) * 64;
    const int nh     = wave & 1;
    const int n_base = nh * 64;

    // XCD-chunked bijective swizzle (grid 4096 % 8 == 0), m fastest within each XCD.
    const int xcd = blockIdx.x & 7;
    const int idx = blockIdx.x >> 3;          // 0..511
    const int bx  = idx & 15;                 // m chunk (fastest)
    const int by  = xcd * 32 + (idx >> 4);    // n panel 0..255
    const int b0  = bx * 128;
    const int n0  = by * 128;

    // staging: lane tid -> phys (row p, chunk cph); content chunk cg = cph ^ ((p>>1)&3)
    // B row-permute: phys row p holds global n_local = ((p&15)<<2) | (p>>4)
    const int p    = tid >> 2;
    const int cph  = tid & 3;
    const int cg   = cph ^ ((p >> 1) & 3);
    const int nrot = ((p & 15) << 2) | (p >> 4);

    const ushort_t* gA0 = f16 + (size_t)(b0 + p) * FDIM + cg * 8;
    const ushort_t* gA1 = f16 + (size_t)(b0 + 64 + p) * FDIM + cg * 8;
    const ushort_t* gB0 = Wb + (size_t)(n0 + nrot) * FDIM + cg * 8;
    const ushort_t* gB1 = Wb + (size_t)(n0 + 64 + nrot) * FDIM + cg * 8;

    // fragment ds_read element offsets (within one buffer)
    int a_off[4], b_off[4];
    #pragma unroll
    for (int mi = 0; mi < 4; mi++) {
        int r = m_base + mi * 16 + l15;
        a_off[mi] = r * 32 + (lg ^ ((r >> 1) & 3)) * 8;
    }
    #pragma unroll
    for (int ni = 0; ni < 4; ni++) {
        int q = n_base + ni * 16 + l15;
        b_off[ni] = q * 32 + (lg ^ ((q >> 1) & 3)) * 8;
    }

    f32x4 acc[4][4];
    #pragma unroll
    for (int mi = 0; mi < 4; mi++)
        #pragma unroll
        for (int ni = 0; ni < 4; ni++)
            acc[mi][ni] = (f32x4){0.f, 0.f, 0.f, 0.f};

    // pipeline: 16 K-tiles, tile t in buf t%2; stage t+1 at top of step t,
    // compute t, then ONE __syncthreads (drain after compute = latency covered).
    STAGE(0, 0)
    __syncthreads();
    #pragma unroll 1
    for (int t2 = 0; t2 < 7; t2++) {
        const int kt = t2 * 2;
        STAGE(1, kt + 1) COMPUTE(0) __syncthreads();
        STAGE(0, kt + 2) COMPUTE(1) __syncthreads();
    }
    STAGE(1, 15) COMPUTE(0) __syncthreads();
    COMPUTE(1)

    // epilogue. D col l15 of frag ni holds global n = n0 + n_base + l15*4 + ni
    // (4 consecutive i per lane). D row = lg*4 + reg -> b. t read as bf16x4 (8B).
    const int c  = n0 >> 9;
    const int iq = (n0 >> 7) & 3;
    const int i_base = (n0 & 511) + n_base + l15 * 4;

    #pragma unroll
    for (int mi = 0; mi < 4; mi++) {
        #pragma unroll
        for (int r = 0; r < 4; r++) {
            int b_idx = b0 + m_base + mi * 16 + lg * 4 + r;
            ushort4 tv = *(const ushort4*)&t16[(size_t)b_idx * FDIM + i_base];
            float sv = acc[mi][0][r] * bf2f(tv.x) + acc[mi][1][r] * bf2f(tv.y)
                     + acc[mi][2][r] * bf2f(tv.z) + acc[mi][3][r] * bf2f(tv.w);
            sv += __shfl_xor(sv, 1, 64);
            sv += __shfl_xor(sv, 2, 64);
            sv += __shfl_xor(sv, 4, 64);
            sv += __shfl_xor(sv, 8, 64);
            if (l15 == 0)
                scratch[(m_base + mi * 16 + lg * 4 + r) * 2 + nh] = sv;
        }
    }
    __syncthreads();
    if (tid < 128) {
        float v = scratch[tid * 2] + scratch[tid * 2 + 1];
        part[(((size_t)(b0 + tid)) * 64 + c) * 4 + iq] = v;
    }
}

// ---- MLP head: 32 threads per batch row, shuffle-reduced ----
__global__ void mlp_kernel(const float* __restrict__ part,
                           const float* __restrict__ b_proj,
                           const float* __restrict__ W1, const float* __restrict__ b1,
                           const float* __restrict__ W2, const float* __restrict__ b2,
                           float* __restrict__ out) {
    __shared__ float h[8][64];
    const int tid = threadIdx.x;
    const int bl  = tid >> 5;        // 0..7
    const int o   = tid & 31;
    const int b   = blockIdx.x * 8 + bl;

    #pragma unroll
    for (int c = o; c < 64; c += 32) {
        float4 v = *(const float4*)&part[(((size_t)b * 64 + c)) * 4];
        float sv = v.x + v.y + v.z + v.w + b_proj[c];
        h[bl][c] = sv > 0.f ? sv : 0.f;
    }
    __syncthreads();

    float sv = b1[o];
    #pragma unroll
    for (int c = 0; c < 64; c++) sv += h[bl][c] * W1[o * 64 + c];
    float v = (sv > 0.f ? sv : 0.f) * W2[o];
    v += __shfl_xor(v, 1, 32);
    v += __shfl_xor(v, 2, 32);
    v += __shfl_xor(v, 4, 32);
    v += __shfl_xor(v, 8, 32);
    v += __shfl_xor(v, 16, 32);
    if (o == 0) out[b] = v + b2[0];
}

extern "C" void kernel_launch(void* const* d_in, const int* in_sizes, int n_in,
                              void* d_out, int out_size, void* d_ws, size_t ws_size,
                              hipStream_t stream) {
    const float* t_feat = (const float*)d_in[0];
    const float* f_feat = (const float*)d_in[1];
    const float* W_proj = (const float*)d_in[2];
    const float* b_proj = (const float*)d_in[3];
    const float* W1     = (const float*)d_in[4];
    const float* b1     = (const float*)d_in[5];
    const float* W2     = (const float*)d_in[6];
    const float* b2     = (const float*)d_in[7];
    float* out = (float*)d_out;

    uint8_t* ws = (uint8_t*)d_ws;
    ushort_t* Wb   = (ushort_t*)(ws);                          // 32 MiB
    ushort_t* f16  = (ushort_t*)(ws + 33554432);               // 2 MiB
    ushort_t* t16  = (ushort_t*)(ws + 33554432 + 2097152);     // 2 MiB
    float*    part = (float*)(ws + 33554432 + 2 * 2097152);    // 2 MiB

    convert_all_kernel<<<dim3(9216), dim3(256), 0, stream>>>(W_proj, Wb, f_feat, f16, t_feat, t16);

    gemm_fused_kernel<<<dim3((BATCH / 128) * ((CDIM * FDIM) / 128)), dim3(256), 0, stream>>>(
        f16, Wb, t16, part);

    mlp_kernel<<<dim3(BATCH / 8), dim3(256), 0, stream>>>(part, b_proj, W1, b1, W2, b2, out);
}